// Round 1
// 439.411 us; speedup vs baseline: 1.0303x; 1.0303x over previous
//
#include <hip/hip_runtime.h>
#include <hip/hip_fp16.h>

#define DD 128            // emb dim, fixed by problem
#define SCAN_CHUNK 1024   // elements per scan1 block

typedef float          f32x4 __attribute__((ext_vector_type(4)));
typedef unsigned int   u32x4 __attribute__((ext_vector_type(4)));
typedef unsigned int   u32x2 __attribute__((ext_vector_type(2)));
typedef unsigned short u16x8 __attribute__((ext_vector_type(8)));

struct __align__(8) Edge { int c; float v; };

// ---- fp16 helpers (RNE pack via v_cvt_f16_f32, unpack via v_cvt_f32_f16) ----
__device__ __forceinline__ unsigned short f2h(float f) {
    return __half_as_ushort(__float2half(f));
}
__device__ __forceinline__ float2 up2(unsigned int u) {
    __half2 h = *reinterpret_cast<const __half2*>(&u);
    return __half22float2(h);
}

// ---- non-temporal access helpers (keep L2 for the gather working set) ----
template <typename T>
__device__ __forceinline__ T ldnt(const T* p) { return __builtin_nontemporal_load(p); }
template <typename T>
__device__ __forceinline__ void stnt(T* p, T v) { __builtin_nontemporal_store(v, p); }

// ---- CSR build ----------------------------------------------------------

__global__ __launch_bounds__(256) void k_zero(int* __restrict__ p, int n) {
    int i = blockIdx.x * 256 + threadIdx.x;
    if (i < n) p[i] = 0;
}

__global__ __launch_bounds__(256) void k_hist(const int* __restrict__ rows,
                                              int* __restrict__ cnt,
                                              int* __restrict__ rank, int E) {
    int e = blockIdx.x * 256 + threadIdx.x;
    if (e < E) {
        int r = ldnt(rows + e);
        int old = atomicAdd(&cnt[r], 1);
        stnt(rank + e, old);
    }
}

// per-block exclusive scan of 1024 elements (4/thread), block totals -> bsum
__global__ __launch_bounds__(256) void k_scan1(int* __restrict__ data,
                                               int* __restrict__ bsum, int n) {
    __shared__ int s[256];
    int tid = threadIdx.x;
    int base = blockIdx.x * SCAN_CHUNK + tid * 4;
    int v0 = 0, v1 = 0, v2 = 0, v3 = 0;
    if (base + 0 < n) v0 = data[base + 0];
    if (base + 1 < n) v1 = data[base + 1];
    if (base + 2 < n) v2 = data[base + 2];
    if (base + 3 < n) v3 = data[base + 3];
    int tsum = v0 + v1 + v2 + v3;
    s[tid] = tsum;
    __syncthreads();
    for (int off = 1; off < 256; off <<= 1) {
        int t = (tid >= off) ? s[tid - off] : 0;
        __syncthreads();
        s[tid] += t;
        __syncthreads();
    }
    int excl = s[tid] - tsum;
    if (tid == 255) bsum[blockIdx.x] = s[255];
    if (base + 0 < n) data[base + 0] = excl;
    if (base + 1 < n) data[base + 1] = excl + v0;
    if (base + 2 < n) data[base + 2] = excl + v0 + v1;
    if (base + 3 < n) data[base + 3] = excl + v0 + v1 + v2;
}

// fused scan2+scan3: each block serially prefixes bsum (nb<=1024) in LDS,
// then adds the proper block offset to its 256 elements.
__global__ __launch_bounds__(256) void k_scan23(int* __restrict__ data,
                                                const int* __restrict__ bsum,
                                                int nb, int n) {
    __shared__ int s[1024];
    int tid = threadIdx.x;
    for (int i = tid; i < nb; i += 256) s[i] = bsum[i];
    __syncthreads();
    if (tid == 0) {
        int run = 0;
        for (int i = 0; i < nb; ++i) { int t = s[i]; s[i] = run; run += t; }
    }
    __syncthreads();
    int i = blockIdx.x * 256 + tid;
    if (i < n) data[i] += s[i >> 10];
}

// no atomics: pos = rowstart[r] + rank[e]; packed 8B write
__global__ __launch_bounds__(256) void k_scatter(const int* __restrict__ rows,
                                                 const int* __restrict__ cols,
                                                 const float* __restrict__ vals,
                                                 const int* __restrict__ rowstart,
                                                 const int* __restrict__ rank,
                                                 Edge* __restrict__ ev, int E) {
    int e = blockIdx.x * 256 + threadIdx.x;
    if (e >= E) return;
    int r = ldnt(rows + e);
    Edge ed;
    ed.c = ldnt(cols + e);
    ed.v = ldnt(vals + e);
    ev[rowstart[r] + rank[e]] = ed;
}

// ---- dense ops ----------------------------------------------------------

// g(fp16) = dropout(src, u), 8 elems/thread. Streams get nt loads; g1 store
// stays cached (it is the next gather's working set).
__global__ __launch_bounds__(256) void k_drop_h(const float* __restrict__ src,
                                                const float* __restrict__ u,
                                                ushort* __restrict__ g, int total8) {
    int i = blockIdx.x * 256 + threadIdx.x;
    if (i >= total8) return;
    const f32x4* s4 = (const f32x4*)src;
    const f32x4* u4 = (const f32x4*)u;
    f32x4 hA = ldnt(s4 + 2 * (size_t)i);
    f32x4 hB = ldnt(s4 + 2 * (size_t)i + 1);
    f32x4 uA = ldnt(u4 + 2 * (size_t)i);
    f32x4 uB = ldnt(u4 + 2 * (size_t)i + 1);
    const float s = 1.0f / 0.9f;
    u16x8 o;
    o[0] = f2h((uA.x >= 0.1f) ? hA.x * s : 0.0f);
    o[1] = f2h((uA.y >= 0.1f) ? hA.y * s : 0.0f);
    o[2] = f2h((uA.z >= 0.1f) ? hA.z * s : 0.0f);
    o[3] = f2h((uA.w >= 0.1f) ? hA.w * s : 0.0f);
    o[4] = f2h((uB.x >= 0.1f) ? hB.x * s : 0.0f);
    o[5] = f2h((uB.y >= 0.1f) ? hB.y * s : 0.0f);
    o[6] = f2h((uB.z >= 0.1f) ? hB.z * s : 0.0f);
    o[7] = f2h((uB.w >= 0.1f) ? hB.w * s : 0.0f);
    ((u16x8*)g)[i] = o;  // normal store: keep resident for the gather
}

// gather SpMM over fp16 src, fp32 accumulate. 16 lanes/row, 8 elems/lane (16B),
// 8-edge unroll -> 8x16B outstanding gathers per lane.
// MODE 1: p16(fp16) = h1 = A*src; g2(fp16) = dropout(h1, u2)
// MODE 2: out(fp32) = (emb + p16in + A*src) / 3
template <int MODE>
__global__ __launch_bounds__(256) void k_gather(const int* __restrict__ rowstart,
                                                const Edge* __restrict__ ev,
                                                const ushort* __restrict__ srch,
                                                const float* __restrict__ u2,
                                                const float* __restrict__ emb,
                                                const ushort* __restrict__ p16in,
                                                ushort* __restrict__ p16out,
                                                ushort* __restrict__ g2,
                                                float* __restrict__ out,
                                                int N, int E) {
    int t = blockIdx.x * 256 + threadIdx.x;
    int row = t >> 4;
    int lane = t & 15;
    if (row >= N) return;
    int start = rowstart[row];
    int end = (row == N - 1) ? E : rowstart[row + 1];
    const u32x4* __restrict__ s4 = (const u32x4*)srch;  // 8 halves per u32x4; 16 per row
    float a0 = 0.f, a1 = 0.f, a2 = 0.f, a3 = 0.f;
    float a4 = 0.f, a5 = 0.f, a6 = 0.f, a7 = 0.f;

#define LDE(i) Edge E##i; { u32x2 q_ = ldnt((const u32x2*)(ev + e + i)); \
                            E##i.c = (int)q_.x; E##i.v = __uint_as_float(q_.y); }
#define GQ(i)  u32x4 q##i = s4[((size_t)E##i.c << 4) + lane];
#define ACC(i) { float vv = E##i.v; \
        float2 w0 = up2(q##i.x), w1 = up2(q##i.y), w2 = up2(q##i.z), w3 = up2(q##i.w); \
        a0 = fmaf(vv, w0.x, a0); a1 = fmaf(vv, w0.y, a1); \
        a2 = fmaf(vv, w1.x, a2); a3 = fmaf(vv, w1.y, a3); \
        a4 = fmaf(vv, w2.x, a4); a5 = fmaf(vv, w2.y, a5); \
        a6 = fmaf(vv, w3.x, a6); a7 = fmaf(vv, w3.y, a7); }

    int e = start;
    for (; e + 8 <= end; e += 8) {
        LDE(0) LDE(1) LDE(2) LDE(3) LDE(4) LDE(5) LDE(6) LDE(7)
        GQ(0) GQ(1) GQ(2) GQ(3) GQ(4) GQ(5) GQ(6) GQ(7)
        ACC(0) ACC(1) ACC(2) ACC(3) ACC(4) ACC(5) ACC(6) ACC(7)
    }
    if (e + 4 <= end) {
        LDE(0) LDE(1) LDE(2) LDE(3)
        GQ(0) GQ(1) GQ(2) GQ(3)
        ACC(0) ACC(1) ACC(2) ACC(3)
        e += 4;
    }
    for (; e < end; ++e) {
        LDE(0) GQ(0) ACC(0)
    }
#undef LDE
#undef GQ
#undef ACC

    size_t o = ((size_t)row << 7) + (size_t)lane * 8;
    if (MODE == 1) {
        const f32x4* u4 = (const f32x4*)(u2 + o);
        f32x4 uA = ldnt(u4);
        f32x4 uB = ldnt(u4 + 1);
        const float s = 1.0f / 0.9f;
        u16x8 gg;
        gg[0] = f2h((uA.x >= 0.1f) ? a0 * s : 0.0f);
        gg[1] = f2h((uA.y >= 0.1f) ? a1 * s : 0.0f);
        gg[2] = f2h((uA.z >= 0.1f) ? a2 * s : 0.0f);
        gg[3] = f2h((uA.w >= 0.1f) ? a3 * s : 0.0f);
        gg[4] = f2h((uB.x >= 0.1f) ? a4 * s : 0.0f);
        gg[5] = f2h((uB.y >= 0.1f) ? a5 * s : 0.0f);
        gg[6] = f2h((uB.z >= 0.1f) ? a6 * s : 0.0f);
        gg[7] = f2h((uB.w >= 0.1f) ? a7 * s : 0.0f);
        stnt((u16x8*)(g2 + o), gg);     // re-read by gather2 as gathered src: but
                                        // written streamed; gather2 will re-warm it
        u16x8 pp;
        pp[0] = f2h(a0); pp[1] = f2h(a1); pp[2] = f2h(a2); pp[3] = f2h(a3);
        pp[4] = f2h(a4); pp[5] = f2h(a5); pp[6] = f2h(a6); pp[7] = f2h(a7);
        stnt((u16x8*)(p16out + o), pp);
    } else {
        f32x4 eA = ldnt((const f32x4*)(emb + o));
        f32x4 eB = ldnt((const f32x4*)(emb + o) + 1);
        u32x4 pq = ldnt((const u32x4*)(p16in + o));
        float2 p0 = up2(pq.x), p1 = up2(pq.y), p2 = up2(pq.z), p3 = up2(pq.w);
        const float t3 = 1.0f / 3.0f;
        f32x4 rA, rB;
        rA.x = (eA.x + p0.x + a0) * t3;
        rA.y = (eA.y + p0.y + a1) * t3;
        rA.z = (eA.z + p1.x + a2) * t3;
        rA.w = (eA.w + p1.y + a3) * t3;
        rB.x = (eB.x + p2.x + a4) * t3;
        rB.y = (eB.y + p2.y + a5) * t3;
        rB.z = (eB.z + p3.x + a6) * t3;
        rB.w = (eB.w + p3.y + a7) * t3;
        stnt((f32x4*)(out + o), rA);
        stnt((f32x4*)(out + o) + 1, rB);
    }
}

// ---- launch -------------------------------------------------------------

extern "C" void kernel_launch(void* const* d_in, const int* in_sizes, int n_in,
                              void* d_out, int out_size, void* d_ws, size_t ws_size,
                              hipStream_t stream) {
    const int* rows = (const int*)d_in[1];
    const int* cols = (const int*)d_in[2];
    const float* vals = (const float*)d_in[3];
    const float* emb = (const float*)d_in[4];
    const float* u1 = (const float*)d_in[5];
    const float* u2 = (const float*)d_in[6];
    float* out = (float*)d_out;

    const int N = in_sizes[0];
    const int E = in_sizes[1];
    const size_t ND = (size_t)N * DD;

    // workspace layout (~97 MB total)
    char* ws = (char*)d_ws;
    ushort* g1  = (ushort*)ws; ws += ND * sizeof(ushort);          // 25.6MB fp16
    ushort* g2  = (ushort*)ws; ws += ND * sizeof(ushort);          // 25.6MB fp16
    ushort* p16 = (ushort*)ws; ws += ND * sizeof(ushort);          // 25.6MB fp16 h1
    int* cnt    = (int*)ws;    ws += (size_t)N * sizeof(int);      // -> rowstart
    int* rank   = (int*)ws;    ws += (size_t)E * sizeof(int);
    Edge* ev    = (Edge*)ws;   ws += (size_t)E * sizeof(Edge);
    int* bsum   = (int*)ws;

    const int total8 = (int)(ND / 8);
    const int gridDrop = (total8 + 255) / 256;
    const int gridE = (E + 255) / 256;
    const int gridN = (N + 255) / 256;
    const int nScanBlocks = (N + SCAN_CHUNK - 1) / SCAN_CHUNK;
    const int gridRow = (int)(((size_t)N * 16 + 255) / 256);

    // CSR build (no float atomics)
    k_zero<<<gridN, 256, 0, stream>>>(cnt, N);
    k_hist<<<gridE, 256, 0, stream>>>(rows, cnt, rank, E);
    k_scan1<<<nScanBlocks, 256, 0, stream>>>(cnt, bsum, N);
    k_scan23<<<gridN, 256, 0, stream>>>(cnt, bsum, nScanBlocks, N);
    k_scatter<<<gridE, 256, 0, stream>>>(rows, cols, vals, cnt, rank, ev, E);

    // layer 1: g1 = dropout(emb,u1)  [fp16]
    k_drop_h<<<gridDrop, 256, 0, stream>>>(emb, u1, g1, total8);
    // h1 = A*g1; p16 = fp16(h1); g2 = dropout(h1,u2) [fp16], fused
    k_gather<1><<<gridRow, 256, 0, stream>>>(cnt, ev, g1, u2, nullptr, nullptr,
                                             p16, g2, nullptr, N, E);
    // layer 2: out = (emb + p16 + A*g2)/3
    k_gather<2><<<gridRow, 256, 0, stream>>>(cnt, ev, g2, nullptr, emb, p16,
                                             nullptr, nullptr, out, N, E);
}